// Round 1
// baseline (432.390 us; speedup 1.0000x reference)
//
#include <hip/hip_runtime.h>
#include <math.h>

// Fixed problem shapes (AdaptiveGraphDeformation_45990509806147)
#define Bn   16
#define Hn   128
#define Wn   128
#define Cn   192
#define C4n  48      // Cn/4
#define HPn  64
#define WPn  64
#define LPn  4096    // HPn*WPn
#define Ln   16384   // Hn*Wn
#define HIDn 64

__device__ __forceinline__ float gelu_exact(float x) {
    return 0.5f * x * (1.0f + erff(x * 0.70710678118654752440f));
}
__device__ __forceinline__ float softplus_f(float x) {
    // matches jax.nn.softplus = logaddexp(x, 0)
    return fmaxf(x, 0.0f) + log1pf(expf(-fabsf(x)));
}

// Kernel 1: 2x2 avg-pool + 2-layer MLP + activations + deformed coords.
// One block handles 16 consecutive pooled positions (same b, same hp row).
// v2: float4 pooling loads (was 48 scalar dwords/thread), ds_read_b128 in the
// MLP loop (was 768 ds_read_b32), s_hid padded +1 (was a 16-way bank conflict
// in the layer-2 loop: stride 256B put all 16 active lanes on one bank).
__global__ __launch_bounds__(256)
void pool_mlp_kernel(const float* __restrict__ feat,
                     const float* __restrict__ W1,
                     const float* __restrict__ b1,
                     const float* __restrict__ W2,
                     const float* __restrict__ b2,
                     const float* __restrict__ wcoef,
                     float* __restrict__ out_params,   // (B, LP, 4)
                     float* __restrict__ out_coords)   // (B, LP, 2)
{
    __shared__ float4 s_pool[16][C4n];        // 16 positions x 192 ch
    __shared__ float  s_hid[16][HIDn + 1];    // +1 pad: layer-2 reads stride 65
    const int t = threadIdx.x;
    const int g0  = blockIdx.x * 16;   // first pooled-position index
    const int b   = g0 >> 12;          // / 4096
    const int lp0 = g0 & 4095;
    const int hp  = lp0 >> 6;
    const int wp0 = lp0 & 63;

    const float4* fb4 = (const float4*)feat + (size_t)b * Ln * C4n;
    const int h0 = hp * 2;

    // ---- pooling: 16 positions x 48 float4 = 768 items, 3 per thread,
    //      each item = 4 float4 loads (the 2x2 pixel block), all coalesced.
#pragma unroll
    for (int k = 0; k < 3; ++k) {
        int v  = t + k * 256;
        int p  = v / C4n;
        int c4 = v - p * C4n;
        int w0 = (wp0 + p) * 2;
        size_t base = ((size_t)h0 * Wn + w0) * C4n + c4;
        float4 x00 = fb4[base];
        float4 x01 = fb4[base + C4n];
        float4 x10 = fb4[base + (size_t)Wn * C4n];
        float4 x11 = fb4[base + (size_t)Wn * C4n + C4n];
        float4 r;
        r.x = 0.25f * (x00.x + x01.x + x10.x + x11.x);
        r.y = 0.25f * (x00.y + x01.y + x10.y + x11.y);
        r.z = 0.25f * (x00.z + x01.z + x10.z + x11.z);
        r.w = 0.25f * (x00.w + x01.w + x10.w + x11.w);
        s_pool[p][c4] = r;
    }
    __syncthreads();

    // ---- hidden layer: thread t computes hidden j = t&63 for 4 positions.
    //      LDS reads are wave-uniform ds_read_b128 broadcasts (conflict-free).
    const int j  = t & 63;
    const int pb = t >> 6;
    float a0 = b1[j], a1 = a0, a2 = a0, a3 = a0;
    for (int c4 = 0; c4 < C4n; ++c4) {
        float4 p0 = s_pool[pb     ][c4];
        float4 p1 = s_pool[pb +  4][c4];
        float4 p2 = s_pool[pb +  8][c4];
        float4 p3 = s_pool[pb + 12][c4];
        const float* wr = W1 + (c4 * 4) * HIDn + j;   // coalesced across wave
        float w0 = wr[0], w1 = wr[HIDn], w2 = wr[2 * HIDn], w3 = wr[3 * HIDn];
        a0 = fmaf(p0.w, w3, fmaf(p0.z, w2, fmaf(p0.y, w1, fmaf(p0.x, w0, a0))));
        a1 = fmaf(p1.w, w3, fmaf(p1.z, w2, fmaf(p1.y, w1, fmaf(p1.x, w0, a1))));
        a2 = fmaf(p2.w, w3, fmaf(p2.z, w2, fmaf(p2.y, w1, fmaf(p2.x, w0, a2))));
        a3 = fmaf(p3.w, w3, fmaf(p3.z, w2, fmaf(p3.y, w1, fmaf(p3.x, w0, a3))));
    }
    s_hid[pb     ][j] = gelu_exact(a0);
    s_hid[pb +  4][j] = gelu_exact(a1);
    s_hid[pb +  8][j] = gelu_exact(a2);
    s_hid[pb + 12][j] = gelu_exact(a3);
    __syncthreads();

    // ---- output layer: 16 positions x 4 outputs = 64 values
    if (t < 64) {
        int p = t >> 2, k = t & 3;
        float acc = b2[k];
        for (int c = 0; c < HIDn; ++c)
            acc = fmaf(s_hid[p][c], W2[c * 4 + k], acc);
        float dp = acc * wcoef[k];
        float val = (k < 2) ? tanhf(dp) : softplus_f(dp);
        int lp = lp0 + p;
        out_params[((size_t)b * LPn + lp) * 4 + k] = val;
        if (k == 0) {
            float ox = 2.0f * (float)(wp0 + p) / 63.0f - 1.0f;
            float dx = ox + val * (2.0f / 64.0f);
            dx = fminf(fmaxf(dx, -1.0f), 1.0f);
            out_coords[((size_t)b * LPn + lp) * 2 + 0] = dx;
        } else if (k == 1) {
            float oy = 2.0f * (float)hp / 63.0f - 1.0f;
            float dy = oy + val * (2.0f / 64.0f);
            dy = fminf(fmaxf(dy, -1.0f), 1.0f);
            out_coords[((size_t)b * LPn + lp) * 2 + 1] = dy;
        }
    }
}

// Kernel 2: bilinear-upsample coords (64->128, align_corners=True) +
// grid_sample (bilinear, border, align_corners=True).
// v2: one block per output row (b,i). Phase 1: 128 threads compute the
// per-pixel sample offsets + bilinear weights ONCE into LDS (was recomputed
// by all 48 c4-threads of each pixel: ~40 VALU + 4 coord gathers, x48
// redundant). Phase 2: 256 threads stream (pixel, c4) float4s -- 4 gathered
// loads + blend + coalesced store, params via LDS broadcast.
__global__ __launch_bounds__(256)
void sample_kernel(const float* __restrict__ feat,
                   const float* __restrict__ coords,  // (B, LP, 2)
                   float* __restrict__ out)           // (B, L, C)
{
    __shared__ int   s_off[4][Wn];   // float4-granular offsets of v00..v11
    __shared__ float s_wx[Wn];
    __shared__ float s_wy[Wn];
    const int t = threadIdx.x;
    const int b = blockIdx.x >> 7;    // B*H = 2048 blocks
    const int i = blockIdx.x & 127;   // output row

    if (t < Wn) {
        const int jj = t;
        // upsample deformed_coords to full res (align_corners=True)
        const float sc = 63.0f / 127.0f;
        float py = i * sc, px = jj * sc;
        float fy0 = floorf(py), fx0 = floorf(px);
        float wy = py - fy0, wx = px - fx0;
        int iy0 = (int)fy0, ix0 = (int)fx0;
        int iy1 = min(iy0 + 1, 63), ix1 = min(ix0 + 1, 63);
        const float2* cm = (const float2*)coords + ((size_t)b << 12);
        float2 c00 = cm[iy0 * 64 + ix0];
        float2 c01 = cm[iy0 * 64 + ix1];
        float2 c10 = cm[iy1 * 64 + ix0];
        float2 c11 = cm[iy1 * 64 + ix1];
        float gx = (c00.x * (1.0f - wy) + c10.x * wy) * (1.0f - wx) +
                   (c01.x * (1.0f - wy) + c11.x * wy) * wx;
        float gy = (c00.y * (1.0f - wy) + c10.y * wy) * (1.0f - wx) +
                   (c01.y * (1.0f - wy) + c11.y * wy) * wx;
        // grid-sample mapping (border padding, align_corners=True)
        float ixf = (gx + 1.0f) * 0.5f * 127.0f;
        float iyf = (gy + 1.0f) * 0.5f * 127.0f;
        ixf = fminf(fmaxf(ixf, 0.0f), 127.0f);
        iyf = fminf(fmaxf(iyf, 0.0f), 127.0f);
        float fx = floorf(ixf), fy = floorf(iyf);
        int sx0 = (int)fx, sy0 = (int)fy;
        int sx1 = min(sx0 + 1, 127), sy1 = min(sy0 + 1, 127);
        s_off[0][jj] = (sy0 * Wn + sx0) * C4n;
        s_off[1][jj] = (sy0 * Wn + sx1) * C4n;
        s_off[2][jj] = (sy1 * Wn + sx0) * C4n;
        s_off[3][jj] = (sy1 * Wn + sx1) * C4n;
        s_wx[jj] = ixf - fx;
        s_wy[jj] = iyf - fy;
    }
    __syncthreads();

    const float4* f4 = (const float4*)feat + ((size_t)b << 14) * C4n;
    float4* o4 = (float4*)out + (((size_t)b << 14) + (size_t)i * Wn) * C4n;

    // 128 pixels x 48 float4 = 6144 elements, 24 per thread.
#pragma unroll 4
    for (int k = 0; k < 24; ++k) {
        int v  = t + k * 256;
        int p  = v / C4n;             // pixel within the row (LDS broadcast idx)
        int c4 = v - p * C4n;
        float swx = s_wx[p], swy = s_wy[p];
        float4 v00 = f4[s_off[0][p] + c4];
        float4 v01 = f4[s_off[1][p] + c4];
        float4 v10 = f4[s_off[2][p] + c4];
        float4 v11 = f4[s_off[3][p] + c4];
        float iwx = 1.0f - swx, iwy = 1.0f - swy;
        float4 r;
        r.x = (v00.x * iwx + v01.x * swx) * iwy + (v10.x * iwx + v11.x * swx) * swy;
        r.y = (v00.y * iwx + v01.y * swx) * iwy + (v10.y * iwx + v11.y * swx) * swy;
        r.z = (v00.z * iwx + v01.z * swx) * iwy + (v10.z * iwx + v11.z * swx) * swy;
        r.w = (v00.w * iwx + v01.w * swx) * iwy + (v10.w * iwx + v11.w * swx) * swy;
        o4[v] = r;
    }
}

extern "C" void kernel_launch(void* const* d_in, const int* in_sizes, int n_in,
                              void* d_out, int out_size, void* d_ws, size_t ws_size,
                              hipStream_t stream) {
    const float* feat = (const float*)d_in[0];
    // d_in[1]=H, d_in[2]=W (scalars; shapes are hard-coded)
    const float* W1 = (const float*)d_in[3];
    const float* b1 = (const float*)d_in[4];
    const float* W2 = (const float*)d_in[5];
    const float* b2 = (const float*)d_in[6];
    const float* wc = (const float*)d_in[7];

    float* out        = (float*)d_out;
    float* out_params = out + (size_t)Bn * Ln * Cn;            // 50331648
    float* out_coords = out_params + (size_t)Bn * LPn * 4;     // +262144

    // 65536 pooled positions / 16 per block
    pool_mlp_kernel<<<(Bn * LPn) / 16, 256, 0, stream>>>(
        feat, W1, b1, W2, b2, wc, out_params, out_coords);

    // one block per output row: B*H = 2048 blocks
    sample_kernel<<<Bn * Hn, 256, 0, stream>>>(feat, out_coords, out);
}

// Round 3
// 401.562 us; speedup vs baseline: 1.0768x; 1.0768x over previous
//
#include <hip/hip_runtime.h>
#include <math.h>

// Fixed problem shapes (AdaptiveGraphDeformation_45990509806147)
#define Bn   16
#define Hn   128
#define Wn   128
#define Cn   192
#define HPn  64
#define WPn  64
#define LPn  4096    // HPn*WPn
#define Ln   16384   // Hn*Wn
#define HIDn 64

typedef float vfloat4 __attribute__((ext_vector_type(4)));  // native vec for nontemporal builtin

__device__ __forceinline__ float gelu_exact(float x) {
    return 0.5f * x * (1.0f + erff(x * 0.70710678118654752440f));
}
__device__ __forceinline__ float softplus_f(float x) {
    // matches jax.nn.softplus = logaddexp(x, 0)
    return fmaxf(x, 0.0f) + log1pf(expf(-fabsf(x)));
}

// Kernel 1: 2x2 avg-pool + 2-layer MLP + activations + deformed coords.
// One block handles 16 consecutive pooled positions (same b, same hp row).
// (v1 structure, unchanged — isolating the k2 store-policy A/B.)
__global__ __launch_bounds__(256)
void pool_mlp_kernel(const float* __restrict__ feat,
                     const float* __restrict__ W1,
                     const float* __restrict__ b1,
                     const float* __restrict__ W2,
                     const float* __restrict__ b2,
                     const float* __restrict__ wcoef,
                     float* __restrict__ out_params,   // (B, LP, 4)
                     float* __restrict__ out_coords)   // (B, LP, 2)
{
    __shared__ float s_pool[16][Cn];
    __shared__ float s_hid[16][HIDn];
    const int t = threadIdx.x;
    const int g0  = blockIdx.x * 16;   // first pooled-position index
    const int b   = g0 >> 12;          // / 4096
    const int lp0 = g0 & 4095;
    const int hp  = lp0 >> 6;
    const int wp0 = lp0 & 63;

    const float* fb = feat + (size_t)b * Ln * Cn;
    const int h0 = hp * 2;

    // ---- pooling: 16 positions x 192 channels = 3072 values, 12 per thread
#pragma unroll
    for (int k = 0; k < 12; ++k) {
        int v = t + k * 256;
        int p = v / Cn;
        int c = v - p * Cn;
        int w0 = (wp0 + p) * 2;
        size_t base = ((size_t)h0 * Wn + w0) * Cn + c;
        float s = fb[base] + fb[base + Cn] + fb[base + (size_t)Wn * Cn] +
                  fb[base + (size_t)Wn * Cn + Cn];
        s_pool[p][c] = 0.25f * s;
    }
    __syncthreads();

    // ---- hidden layer: thread t computes hidden j = t&63 for 4 positions
    const int j  = t & 63;
    const int pb = t >> 6;
    float a0 = b1[j], a1 = a0, a2 = a0, a3 = a0;
    for (int c = 0; c < Cn; ++c) {
        float w = W1[c * HIDn + j];        // coalesced across the wave
        a0 = fmaf(s_pool[pb     ][c], w, a0);   // LDS broadcast reads
        a1 = fmaf(s_pool[pb +  4][c], w, a1);
        a2 = fmaf(s_pool[pb +  8][c], w, a2);
        a3 = fmaf(s_pool[pb + 12][c], w, a3);
    }
    s_hid[pb     ][j] = gelu_exact(a0);
    s_hid[pb +  4][j] = gelu_exact(a1);
    s_hid[pb +  8][j] = gelu_exact(a2);
    s_hid[pb + 12][j] = gelu_exact(a3);
    __syncthreads();

    // ---- output layer: 16 positions x 4 outputs = 64 values
    if (t < 64) {
        int p = t >> 2, k = t & 3;
        float acc = b2[k];
        for (int c = 0; c < HIDn; ++c)
            acc = fmaf(s_hid[p][c], W2[c * 4 + k], acc);
        float dp = acc * wcoef[k];
        float val = (k < 2) ? tanhf(dp) : softplus_f(dp);
        int lp = lp0 + p;
        out_params[((size_t)b * LPn + lp) * 4 + k] = val;
        if (k == 0) {
            float ox = 2.0f * (float)(wp0 + p) / 63.0f - 1.0f;
            float dx = ox + val * (2.0f / 64.0f);
            dx = fminf(fmaxf(dx, -1.0f), 1.0f);
            out_coords[((size_t)b * LPn + lp) * 2 + 0] = dx;
        } else if (k == 1) {
            float oy = 2.0f * (float)hp / 63.0f - 1.0f;
            float dy = oy + val * (2.0f / 64.0f);
            dy = fminf(fmaxf(dy, -1.0f), 1.0f);
            out_coords[((size_t)b * LPn + lp) * 2 + 1] = dy;
        }
    }
}

// Kernel 2: bilinear-upsample coords (64->128, align_corners=True) +
// grid_sample (bilinear, border, align_corners=True).
// One thread per (pixel, c4) float4 of the output. (v1 structure.)
// v3 change (ONLY change vs v1): output stores are NON-TEMPORAL so the
// 201 MB write stream does not evict feat from the 256 MB L3 while we are
// still gathering from it (reuse distance of feat ~ L3 capacity).
__global__ __launch_bounds__(256)
void sample_kernel(const float* __restrict__ feat,
                   const float* __restrict__ coords,  // (B, LP, 2)
                   float* __restrict__ out)           // (B, L, C)
{
    const int idx = blockIdx.x * 256 + threadIdx.x;   // < B*H*W*48
    const int pix = idx / 48;
    const int c4  = idx - pix * 48;
    const int b   = pix >> 14;          // / (H*W)
    const int rem = pix & 16383;
    const int i   = rem >> 7;           // output row
    const int jj  = rem & 127;          // output col

    // ---- upsample deformed_coords to full res (align_corners=True)
    const float sc = 63.0f / 127.0f;
    float py = i * sc, px = jj * sc;
    float fy0 = floorf(py), fx0 = floorf(px);
    float wy = py - fy0, wx = px - fx0;
    int iy0 = (int)fy0, ix0 = (int)fx0;
    int iy1 = min(iy0 + 1, 63), ix1 = min(ix0 + 1, 63);
    const float2* cm = (const float2*)coords + ((size_t)b << 12);
    float2 c00 = cm[iy0 * 64 + ix0];
    float2 c01 = cm[iy0 * 64 + ix1];
    float2 c10 = cm[iy1 * 64 + ix0];
    float2 c11 = cm[iy1 * 64 + ix1];
    float gx = (c00.x * (1.0f - wy) + c10.x * wy) * (1.0f - wx) +
               (c01.x * (1.0f - wy) + c11.x * wy) * wx;
    float gy = (c00.y * (1.0f - wy) + c10.y * wy) * (1.0f - wx) +
               (c01.y * (1.0f - wy) + c11.y * wy) * wx;

    // ---- grid sample mapping
    float ix = (gx + 1.0f) * 0.5f * 127.0f;
    float iy = (gy + 1.0f) * 0.5f * 127.0f;
    ix = fminf(fmaxf(ix, 0.0f), 127.0f);
    iy = fminf(fmaxf(iy, 0.0f), 127.0f);
    float fx = floorf(ix), fy = floorf(iy);
    float swx = ix - fx, swy = iy - fy;
    int sx0 = (int)fx, sy0 = (int)fy;
    int sx1 = min(sx0 + 1, 127), sy1 = min(sy0 + 1, 127);

    const float4* f4 = (const float4*)feat + ((size_t)b << 14) * 48;
    float4 v00 = f4[(sy0 * 128 + sx0) * 48 + c4];
    float4 v01 = f4[(sy0 * 128 + sx1) * 48 + c4];
    float4 v10 = f4[(sy1 * 128 + sx0) * 48 + c4];
    float4 v11 = f4[(sy1 * 128 + sx1) * 48 + c4];

    float iwx = 1.0f - swx, iwy = 1.0f - swy;
    vfloat4 r;
    r.x = (v00.x * iwx + v01.x * swx) * iwy + (v10.x * iwx + v11.x * swx) * swy;
    r.y = (v00.y * iwx + v01.y * swx) * iwy + (v10.y * iwx + v11.y * swx) * swy;
    r.z = (v00.z * iwx + v01.z * swx) * iwy + (v10.z * iwx + v11.z * swx) * swy;
    r.w = (v00.w * iwx + v01.w * swx) * iwy + (v10.w * iwx + v11.w * swx) * swy;
    __builtin_nontemporal_store(r, (vfloat4*)out + idx);
}

extern "C" void kernel_launch(void* const* d_in, const int* in_sizes, int n_in,
                              void* d_out, int out_size, void* d_ws, size_t ws_size,
                              hipStream_t stream) {
    const float* feat = (const float*)d_in[0];
    // d_in[1]=H, d_in[2]=W (scalars; shapes are hard-coded)
    const float* W1 = (const float*)d_in[3];
    const float* b1 = (const float*)d_in[4];
    const float* W2 = (const float*)d_in[5];
    const float* b2 = (const float*)d_in[6];
    const float* wc = (const float*)d_in[7];

    float* out        = (float*)d_out;
    float* out_params = out + (size_t)Bn * Ln * Cn;            // 50331648
    float* out_coords = out_params + (size_t)Bn * LPn * 4;     // +262144

    // 65536 pooled positions / 16 per block
    pool_mlp_kernel<<<(Bn * LPn) / 16, 256, 0, stream>>>(
        feat, W1, b1, W2, b2, wc, out_params, out_coords);

    // B*H*W*48 float4 outputs, 256 threads/block -> 49152 blocks exactly
    sample_kernel<<<(Bn * Hn * Wn * 48) / 256, 256, 0, stream>>>(
        feat, out_coords, out);
}

// Round 4
// 395.852 us; speedup vs baseline: 1.0923x; 1.0144x over previous
//
#include <hip/hip_runtime.h>
#include <math.h>

// Fixed problem shapes (AdaptiveGraphDeformation_45990509806147)
#define Bn   16
#define Hn   128
#define Wn   128
#define Cn   192
#define C4n  48      // Cn/4
#define HPn  64
#define WPn  64
#define LPn  4096    // HPn*WPn
#define Ln   16384   // Hn*Wn
#define HIDn 64

typedef float vfloat4 __attribute__((ext_vector_type(4)));  // native vec for nontemporal builtin

__device__ __forceinline__ float gelu_exact(float x) {
    return 0.5f * x * (1.0f + erff(x * 0.70710678118654752440f));
}
__device__ __forceinline__ float softplus_f(float x) {
    // matches jax.nn.softplus = logaddexp(x, 0)
    return fmaxf(x, 0.0f) + log1pf(expf(-fabsf(x)));
}

// Kernel 1: 2x2 avg-pool + 2-layer MLP + activations + deformed coords.
// One block handles 16 consecutive pooled positions (same b, same hp row).
// v4 (isolated k1 changes on top of the v3 winner):
//  - pooling loads vectorized to float4 (48 scalar dwords -> 12 dwordx4/thread)
//  - layer-1 LDS reads vectorized (768 ds_read_b32 -> 192 ds_read_b128)
//  - s_hid padded +1 (layer-2 stride-256B 16-way bank conflict -> spread)
__global__ __launch_bounds__(256)
void pool_mlp_kernel(const float* __restrict__ feat,
                     const float* __restrict__ W1,
                     const float* __restrict__ b1,
                     const float* __restrict__ W2,
                     const float* __restrict__ b2,
                     const float* __restrict__ wcoef,
                     float* __restrict__ out_params,   // (B, LP, 4)
                     float* __restrict__ out_coords)   // (B, LP, 2)
{
    __shared__ float4 s_pool[16][C4n];        // 16 positions x 192 ch (as float4)
    __shared__ float  s_hid[16][HIDn + 1];    // +1 pad: layer-2 reads stride 65
    const int t = threadIdx.x;
    const int g0  = blockIdx.x * 16;   // first pooled-position index
    const int b   = g0 >> 12;          // / 4096
    const int lp0 = g0 & 4095;
    const int hp  = lp0 >> 6;
    const int wp0 = lp0 & 63;

    const float4* fb4 = (const float4*)feat + (size_t)b * Ln * C4n;
    const int h0 = hp * 2;

    // ---- pooling: 16 positions x 48 float4 = 768 items, 3 per thread
#pragma unroll
    for (int k = 0; k < 3; ++k) {
        int v  = t + k * 256;
        int p  = v / C4n;
        int c4 = v - p * C4n;
        int w0 = (wp0 + p) * 2;
        size_t base = ((size_t)h0 * Wn + w0) * C4n + c4;
        float4 x00 = fb4[base];
        float4 x01 = fb4[base + C4n];
        float4 x10 = fb4[base + (size_t)Wn * C4n];
        float4 x11 = fb4[base + (size_t)Wn * C4n + C4n];
        float4 r;
        r.x = 0.25f * (x00.x + x01.x + x10.x + x11.x);
        r.y = 0.25f * (x00.y + x01.y + x10.y + x11.y);
        r.z = 0.25f * (x00.z + x01.z + x10.z + x11.z);
        r.w = 0.25f * (x00.w + x01.w + x10.w + x11.w);
        s_pool[p][c4] = r;
    }
    __syncthreads();

    // ---- hidden layer: thread t computes hidden j = t&63 for 4 positions.
    //      LDS reads are wave-uniform ds_read_b128 broadcasts (conflict-free).
    const int j  = t & 63;
    const int pb = t >> 6;
    float a0 = b1[j], a1 = a0, a2 = a0, a3 = a0;
    for (int c4 = 0; c4 < C4n; ++c4) {
        float4 p0 = s_pool[pb     ][c4];
        float4 p1 = s_pool[pb +  4][c4];
        float4 p2 = s_pool[pb +  8][c4];
        float4 p3 = s_pool[pb + 12][c4];
        const float* wr = W1 + (c4 * 4) * HIDn + j;   // 4 coalesced 256B rows
        float w0 = wr[0], w1 = wr[HIDn], w2 = wr[2 * HIDn], w3 = wr[3 * HIDn];
        a0 = fmaf(p0.w, w3, fmaf(p0.z, w2, fmaf(p0.y, w1, fmaf(p0.x, w0, a0))));
        a1 = fmaf(p1.w, w3, fmaf(p1.z, w2, fmaf(p1.y, w1, fmaf(p1.x, w0, a1))));
        a2 = fmaf(p2.w, w3, fmaf(p2.z, w2, fmaf(p2.y, w1, fmaf(p2.x, w0, a2))));
        a3 = fmaf(p3.w, w3, fmaf(p3.z, w2, fmaf(p3.y, w1, fmaf(p3.x, w0, a3))));
    }
    s_hid[pb     ][j] = gelu_exact(a0);
    s_hid[pb +  4][j] = gelu_exact(a1);
    s_hid[pb +  8][j] = gelu_exact(a2);
    s_hid[pb + 12][j] = gelu_exact(a3);
    __syncthreads();

    // ---- output layer: 16 positions x 4 outputs = 64 values
    if (t < 64) {
        int p = t >> 2, k = t & 3;
        float acc = b2[k];
        for (int c = 0; c < HIDn; ++c)
            acc = fmaf(s_hid[p][c], W2[c * 4 + k], acc);
        float dp = acc * wcoef[k];
        float val = (k < 2) ? tanhf(dp) : softplus_f(dp);
        int lp = lp0 + p;
        out_params[((size_t)b * LPn + lp) * 4 + k] = val;
        if (k == 0) {
            float ox = 2.0f * (float)(wp0 + p) / 63.0f - 1.0f;
            float dx = ox + val * (2.0f / 64.0f);
            dx = fminf(fmaxf(dx, -1.0f), 1.0f);
            out_coords[((size_t)b * LPn + lp) * 2 + 0] = dx;
        } else if (k == 1) {
            float oy = 2.0f * (float)hp / 63.0f - 1.0f;
            float dy = oy + val * (2.0f / 64.0f);
            dy = fminf(fmaxf(dy, -1.0f), 1.0f);
            out_coords[((size_t)b * LPn + lp) * 2 + 1] = dy;
        }
    }
}

// Kernel 2: bilinear-upsample coords (64->128, align_corners=True) +
// grid_sample (bilinear, border, align_corners=True).
// One thread per (pixel, c4) float4 of the output. (v3 winner — unchanged.)
// Non-temporal output stores keep feat L3-resident during the gathers.
__global__ __launch_bounds__(256)
void sample_kernel(const float* __restrict__ feat,
                   const float* __restrict__ coords,  // (B, LP, 2)
                   float* __restrict__ out)           // (B, L, C)
{
    const int idx = blockIdx.x * 256 + threadIdx.x;   // < B*H*W*48
    const int pix = idx / 48;
    const int c4  = idx - pix * 48;
    const int b   = pix >> 14;          // / (H*W)
    const int rem = pix & 16383;
    const int i   = rem >> 7;           // output row
    const int jj  = rem & 127;          // output col

    // ---- upsample deformed_coords to full res (align_corners=True)
    const float sc = 63.0f / 127.0f;
    float py = i * sc, px = jj * sc;
    float fy0 = floorf(py), fx0 = floorf(px);
    float wy = py - fy0, wx = px - fx0;
    int iy0 = (int)fy0, ix0 = (int)fx0;
    int iy1 = min(iy0 + 1, 63), ix1 = min(ix0 + 1, 63);
    const float2* cm = (const float2*)coords + ((size_t)b << 12);
    float2 c00 = cm[iy0 * 64 + ix0];
    float2 c01 = cm[iy0 * 64 + ix1];
    float2 c10 = cm[iy1 * 64 + ix0];
    float2 c11 = cm[iy1 * 64 + ix1];
    float gx = (c00.x * (1.0f - wy) + c10.x * wy) * (1.0f - wx) +
               (c01.x * (1.0f - wy) + c11.x * wy) * wx;
    float gy = (c00.y * (1.0f - wy) + c10.y * wy) * (1.0f - wx) +
               (c01.y * (1.0f - wy) + c11.y * wy) * wx;

    // ---- grid sample mapping
    float ix = (gx + 1.0f) * 0.5f * 127.0f;
    float iy = (gy + 1.0f) * 0.5f * 127.0f;
    ix = fminf(fmaxf(ix, 0.0f), 127.0f);
    iy = fminf(fmaxf(iy, 0.0f), 127.0f);
    float fx = floorf(ix), fy = floorf(iy);
    float swx = ix - fx, swy = iy - fy;
    int sx0 = (int)fx, sy0 = (int)fy;
    int sx1 = min(sx0 + 1, 127), sy1 = min(sy0 + 1, 127);

    const float4* f4 = (const float4*)feat + ((size_t)b << 14) * 48;
    float4 v00 = f4[(sy0 * 128 + sx0) * 48 + c4];
    float4 v01 = f4[(sy0 * 128 + sx1) * 48 + c4];
    float4 v10 = f4[(sy1 * 128 + sx0) * 48 + c4];
    float4 v11 = f4[(sy1 * 128 + sx1) * 48 + c4];

    float iwx = 1.0f - swx, iwy = 1.0f - swy;
    vfloat4 r;
    r.x = (v00.x * iwx + v01.x * swx) * iwy + (v10.x * iwx + v11.x * swx) * swy;
    r.y = (v00.y * iwx + v01.y * swx) * iwy + (v10.y * iwx + v11.y * swx) * swy;
    r.z = (v00.z * iwx + v01.z * swx) * iwy + (v10.z * iwx + v11.z * swx) * swy;
    r.w = (v00.w * iwx + v01.w * swx) * iwy + (v10.w * iwx + v11.w * swx) * swy;
    __builtin_nontemporal_store(r, (vfloat4*)out + idx);
}

extern "C" void kernel_launch(void* const* d_in, const int* in_sizes, int n_in,
                              void* d_out, int out_size, void* d_ws, size_t ws_size,
                              hipStream_t stream) {
    const float* feat = (const float*)d_in[0];
    // d_in[1]=H, d_in[2]=W (scalars; shapes are hard-coded)
    const float* W1 = (const float*)d_in[3];
    const float* b1 = (const float*)d_in[4];
    const float* W2 = (const float*)d_in[5];
    const float* b2 = (const float*)d_in[6];
    const float* wc = (const float*)d_in[7];

    float* out        = (float*)d_out;
    float* out_params = out + (size_t)Bn * Ln * Cn;            // 50331648
    float* out_coords = out_params + (size_t)Bn * LPn * 4;     // +262144

    // 65536 pooled positions / 16 per block
    pool_mlp_kernel<<<(Bn * LPn) / 16, 256, 0, stream>>>(
        feat, W1, b1, W2, b2, wc, out_params, out_coords);

    // B*H*W*48 float4 outputs, 256 threads/block -> 49152 blocks exactly
    sample_kernel<<<(Bn * Hn * Wn * 48) / 256, 256, 0, stream>>>(
        feat, out_coords, out);
}

// Round 7
// 384.339 us; speedup vs baseline: 1.1250x; 1.0300x over previous
//
#include <hip/hip_runtime.h>
#include <math.h>

// Fixed problem shapes (AdaptiveGraphDeformation_45990509806147)
#define Bn   16
#define Hn   128
#define Wn   128
#define Cn   192
#define C4n  48      // Cn/4
#define HPn  64
#define WPn  64
#define LPn  4096    // HPn*WPn
#define Ln   16384   // Hn*Wn
#define HIDn 64

typedef float vfloat4 __attribute__((ext_vector_type(4)));  // native vec for nontemporal builtin

__device__ __forceinline__ float gelu_exact(float x) {
    return 0.5f * x * (1.0f + erff(x * 0.70710678118654752440f));
}
__device__ __forceinline__ float softplus_f(float x) {
    // matches jax.nn.softplus = logaddexp(x, 0)
    return fmaxf(x, 0.0f) + log1pf(expf(-fabsf(x)));
}

// Kernel 1: 2x2 avg-pool + 2-layer MLP + activations + deformed coords.
// (v4 structure — float4 pooling, ds_read_b128 MLP, padded s_hid. Unchanged.)
__global__ __launch_bounds__(256)
void pool_mlp_kernel(const float* __restrict__ feat,
                     const float* __restrict__ W1,
                     const float* __restrict__ b1,
                     const float* __restrict__ W2,
                     const float* __restrict__ b2,
                     const float* __restrict__ wcoef,
                     float* __restrict__ out_params,   // (B, LP, 4)
                     float* __restrict__ out_coords)   // (B, LP, 2)
{
    __shared__ float4 s_pool[16][C4n];        // 16 positions x 192 ch (as float4)
    __shared__ float  s_hid[16][HIDn + 1];    // +1 pad: layer-2 reads stride 65
    const int t = threadIdx.x;
    const int g0  = blockIdx.x * 16;   // first pooled-position index
    const int b   = g0 >> 12;          // / 4096
    const int lp0 = g0 & 4095;
    const int hp  = lp0 >> 6;
    const int wp0 = lp0 & 63;

    const float4* fb4 = (const float4*)feat + (size_t)b * Ln * C4n;
    const int h0 = hp * 2;

    // ---- pooling: 16 positions x 48 float4 = 768 items, 3 per thread
#pragma unroll
    for (int k = 0; k < 3; ++k) {
        int v  = t + k * 256;
        int p  = v / C4n;
        int c4 = v - p * C4n;
        int w0 = (wp0 + p) * 2;
        size_t base = ((size_t)h0 * Wn + w0) * C4n + c4;
        float4 x00 = fb4[base];
        float4 x01 = fb4[base + C4n];
        float4 x10 = fb4[base + (size_t)Wn * C4n];
        float4 x11 = fb4[base + (size_t)Wn * C4n + C4n];
        float4 r;
        r.x = 0.25f * (x00.x + x01.x + x10.x + x11.x);
        r.y = 0.25f * (x00.y + x01.y + x10.y + x11.y);
        r.z = 0.25f * (x00.z + x01.z + x10.z + x11.z);
        r.w = 0.25f * (x00.w + x01.w + x10.w + x11.w);
        s_pool[p][c4] = r;
    }
    __syncthreads();

    // ---- hidden layer: thread t computes hidden j = t&63 for 4 positions.
    const int j  = t & 63;
    const int pb = t >> 6;
    float a0 = b1[j], a1 = a0, a2 = a0, a3 = a0;
    for (int c4 = 0; c4 < C4n; ++c4) {
        float4 p0 = s_pool[pb     ][c4];
        float4 p1 = s_pool[pb +  4][c4];
        float4 p2 = s_pool[pb +  8][c4];
        float4 p3 = s_pool[pb + 12][c4];
        const float* wr = W1 + (c4 * 4) * HIDn + j;   // 4 coalesced 256B rows
        float w0 = wr[0], w1 = wr[HIDn], w2 = wr[2 * HIDn], w3 = wr[3 * HIDn];
        a0 = fmaf(p0.w, w3, fmaf(p0.z, w2, fmaf(p0.y, w1, fmaf(p0.x, w0, a0))));
        a1 = fmaf(p1.w, w3, fmaf(p1.z, w2, fmaf(p1.y, w1, fmaf(p1.x, w0, a1))));
        a2 = fmaf(p2.w, w3, fmaf(p2.z, w2, fmaf(p2.y, w1, fmaf(p2.x, w0, a2))));
        a3 = fmaf(p3.w, w3, fmaf(p3.z, w2, fmaf(p3.y, w1, fmaf(p3.x, w0, a3))));
    }
    s_hid[pb     ][j] = gelu_exact(a0);
    s_hid[pb +  4][j] = gelu_exact(a1);
    s_hid[pb +  8][j] = gelu_exact(a2);
    s_hid[pb + 12][j] = gelu_exact(a3);
    __syncthreads();

    // ---- output layer: 16 positions x 4 outputs = 64 values
    if (t < 64) {
        int p = t >> 2, k = t & 3;
        float acc = b2[k];
        for (int c = 0; c < HIDn; ++c)
            acc = fmaf(s_hid[p][c], W2[c * 4 + k], acc);
        float dp = acc * wcoef[k];
        float val = (k < 2) ? tanhf(dp) : softplus_f(dp);
        int lp = lp0 + p;
        out_params[((size_t)b * LPn + lp) * 4 + k] = val;
        if (k == 0) {
            float ox = 2.0f * (float)(wp0 + p) / 63.0f - 1.0f;
            float dx = ox + val * (2.0f / 64.0f);
            dx = fminf(fmaxf(dx, -1.0f), 1.0f);
            out_coords[((size_t)b * LPn + lp) * 2 + 0] = dx;
        } else if (k == 1) {
            float oy = 2.0f * (float)hp / 63.0f - 1.0f;
            float dy = oy + val * (2.0f / 64.0f);
            dy = fminf(fmaxf(dy, -1.0f), 1.0f);
            out_coords[((size_t)b * LPn + lp) * 2 + 1] = dy;
        }
    }
}

// Kernel 2: bilinear-upsample coords + grid_sample (border, align_corners).
// One thread per (pixel, c4) float4 of the output; nt stores (v3 winner).
// v5 change (ONLY change): bijective XCD-aware block swizzle. Default
// round-robin dispatch puts consecutive blocks (same image region) on
// different XCDs, so all 8 private L2s pull nearly the whole 201 MB feat
// from L3 (~1.6 GB of L3->L2 traffic). Swizzled, each XCD owns a
// contiguous 1/8 of the grid = exactly 2 images -> ~25 MB per L2.
#define K2_NWG   49152   // (Bn*Hn*Wn*48)/256, divisible by 8
#define K2_CHUNK (K2_NWG / 8)
__global__ __launch_bounds__(256)
void sample_kernel(const float* __restrict__ feat,
                   const float* __restrict__ coords,  // (B, LP, 2)
                   float* __restrict__ out)           // (B, L, C)
{
    const int bid = blockIdx.x;
    const int swz = (bid & 7) * K2_CHUNK + (bid >> 3);   // bijective (nwg%8==0)
    const int idx = swz * 256 + threadIdx.x;   // < B*H*W*48
    const int pix = idx / 48;
    const int c4  = idx - pix * 48;
    const int b   = pix >> 14;          // / (H*W)
    const int rem = pix & 16383;
    const int i   = rem >> 7;           // output row
    const int jj  = rem & 127;          // output col

    // ---- upsample deformed_coords to full res (align_corners=True)
    const float sc = 63.0f / 127.0f;
    float py = i * sc, px = jj * sc;
    float fy0 = floorf(py), fx0 = floorf(px);
    float wy = py - fy0, wx = px - fx0;
    int iy0 = (int)fy0, ix0 = (int)fx0;
    int iy1 = min(iy0 + 1, 63), ix1 = min(ix0 + 1, 63);
    const float2* cm = (const float2*)coords + ((size_t)b << 12);
    float2 c00 = cm[iy0 * 64 + ix0];
    float2 c01 = cm[iy0 * 64 + ix1];
    float2 c10 = cm[iy1 * 64 + ix0];
    float2 c11 = cm[iy1 * 64 + ix1];
    float gx = (c00.x * (1.0f - wy) + c10.x * wy) * (1.0f - wx) +
               (c01.x * (1.0f - wy) + c11.x * wy) * wx;
    float gy = (c00.y * (1.0f - wy) + c10.y * wy) * (1.0f - wx) +
               (c01.y * (1.0f - wy) + c11.y * wy) * wx;

    // ---- grid sample mapping
    float ix = (gx + 1.0f) * 0.5f * 127.0f;
    float iy = (gy + 1.0f) * 0.5f * 127.0f;
    ix = fminf(fmaxf(ix, 0.0f), 127.0f);
    iy = fminf(fmaxf(iy, 0.0f), 127.0f);
    float fx = floorf(ix), fy = floorf(iy);
    float swx = ix - fx, swy = iy - fy;
    int sx0 = (int)fx, sy0 = (int)fy;
    int sx1 = min(sx0 + 1, 127), sy1 = min(sy0 + 1, 127);

    const float4* f4 = (const float4*)feat + ((size_t)b << 14) * 48;
    float4 v00 = f4[(sy0 * 128 + sx0) * 48 + c4];
    float4 v01 = f4[(sy0 * 128 + sx1) * 48 + c4];
    float4 v10 = f4[(sy1 * 128 + sx0) * 48 + c4];
    float4 v11 = f4[(sy1 * 128 + sx1) * 48 + c4];

    float iwx = 1.0f - swx, iwy = 1.0f - swy;
    vfloat4 r;
    r.x = (v00.x * iwx + v01.x * swx) * iwy + (v10.x * iwx + v11.x * swx) * swy;
    r.y = (v00.y * iwx + v01.y * swx) * iwy + (v10.y * iwx + v11.y * swx) * swy;
    r.z = (v00.z * iwx + v01.z * swx) * iwy + (v10.z * iwx + v11.z * swx) * swy;
    r.w = (v00.w * iwx + v01.w * swx) * iwy + (v10.w * iwx + v11.w * swx) * swy;
    __builtin_nontemporal_store(r, (vfloat4*)out + idx);
}

extern "C" void kernel_launch(void* const* d_in, const int* in_sizes, int n_in,
                              void* d_out, int out_size, void* d_ws, size_t ws_size,
                              hipStream_t stream) {
    const float* feat = (const float*)d_in[0];
    // d_in[1]=H, d_in[2]=W (scalars; shapes are hard-coded)
    const float* W1 = (const float*)d_in[3];
    const float* b1 = (const float*)d_in[4];
    const float* W2 = (const float*)d_in[5];
    const float* b2 = (const float*)d_in[6];
    const float* wc = (const float*)d_in[7];

    float* out        = (float*)d_out;
    float* out_params = out + (size_t)Bn * Ln * Cn;            // 50331648
    float* out_coords = out_params + (size_t)Bn * LPn * 4;     // +262144

    // 65536 pooled positions / 16 per block
    pool_mlp_kernel<<<(Bn * LPn) / 16, 256, 0, stream>>>(
        feat, W1, b1, W2, b2, wc, out_params, out_coords);

    // B*H*W*48 float4 outputs, 256 threads/block -> 49152 blocks exactly
    sample_kernel<<<K2_NWG, 256, 0, stream>>>(feat, out_coords, out);
}